// Round 15
// baseline (402.178 us; speedup 1.0000x reference)
//
#include <hip/hip_runtime.h>
#include <hip/hip_bf16.h>

#define NN 100000
#define NE 1600000
#define NP 500000
#define C 128
#define NBUCK 782              // buckets of 128 dst nodes: 782*128 = 100096 >= NN

typedef __attribute__((ext_vector_type(4))) float f32x4;
typedef _Float16 f16;
typedef __attribute__((ext_vector_type(4))) _Float16 f16x4;
typedef __attribute__((ext_vector_type(8))) _Float16 f16x8;

// ---------- f32 -> f16 conversion ----------
__global__ __launch_bounds__(256) void f32_to_f16_kernel(
        const float* __restrict__ in, f16* __restrict__ out, int n4) {
    int i = blockIdx.x * 256 + threadIdx.x;
    if (i < n4) {
        float4 v = *(const float4*)&in[i * 4];
        f16x4 h = {(f16)v.x, (f16)v.y, (f16)v.z, (f16)v.w};
        *(f16x4*)&out[i * 4] = h;
    }
}

// ---------- bucket histogram (LDS-staged) ----------
__global__ __launch_bounds__(256) void bin_count_kernel(
        const int* __restrict__ dst, int* __restrict__ gcnt, int nE) {
    __shared__ int h[NBUCK];
    int tid = threadIdx.x;
    for (int i = tid; i < NBUCK; i += 256) h[i] = 0;
    __syncthreads();
    int base = blockIdx.x * 8192;
#pragma unroll
    for (int j = 0; j < 32; ++j) {
        int e = base + tid + j * 256;
        if (e < nE) atomicAdd(&h[dst[e] >> 7], 1);
    }
    __syncthreads();
    for (int i = tid; i < NBUCK; i += 256)
        if (h[i]) atomicAdd(&gcnt[i], h[i]);
}

// ---------- scan bucket counts (one block) ----------
__global__ __launch_bounds__(1024) void bin_scan_kernel(
        const int* __restrict__ gcnt, int* __restrict__ gstart,
        int* __restrict__ gcursor) {
    __shared__ int s[1024];
    int tid = threadIdx.x;
    int v = (tid < NBUCK) ? gcnt[tid] : 0;
    s[tid] = v;
    __syncthreads();
    for (int off = 1; off < 1024; off <<= 1) {
        int t = (tid >= off) ? s[tid - off] : 0;
        __syncthreads();
        s[tid] += t;
        __syncthreads();
    }
    int excl = s[tid] - v;
    if (tid < NBUCK) { gstart[tid] = excl; gcursor[tid] = excl; }
    if (tid == NBUCK - 1) gstart[NBUCK] = excl + v;
}

// ---------- LDS-staged multisplit scatter: coalesced bucket-grouped writes ----------
__global__ __launch_bounds__(256) void bin_scatter_kernel(
        const int* __restrict__ src, const int* __restrict__ dst,
        int* __restrict__ gcursor, unsigned* __restrict__ elist, int nE) {
    __shared__ unsigned stage[4096];
    __shared__ unsigned short sbkt[4096];
    __shared__ int h[NBUCK];
    __shared__ int ex[NBUCK];
    __shared__ int gb[NBUCK];
    __shared__ int psum[256];
    int tid = threadIdx.x;
    for (int i = tid; i < NBUCK; i += 256) h[i] = 0;
    __syncthreads();
    int base = blockIdx.x * 4096;
    unsigned pk[16]; int bk[16];
#pragma unroll
    for (int j = 0; j < 16; ++j) {
        int e = base + tid + j * 256;
        bool ok = e < nE;
        int d = ok ? dst[e] : 0;
        int s = ok ? src[e] : 0;
        bk[j] = ok ? (d >> 7) : -1;
        pk[j] = ((unsigned)(d & 127) << 17) | (unsigned)s;
        if (ok) atomicAdd(&h[bk[j]], 1);
    }
    __syncthreads();
    int lo = tid * 4;
    int c4[4]; int sum = 0;
#pragma unroll
    for (int j = 0; j < 4; ++j) {
        int idx = lo + j;
        c4[j] = (idx < NBUCK) ? h[idx] : 0;
        sum += c4[j];
    }
    psum[tid] = sum;
    __syncthreads();
    for (int off = 1; off < 256; off <<= 1) {
        int t = (tid >= off) ? psum[tid - off] : 0;
        __syncthreads();
        psum[tid] += t;
        __syncthreads();
    }
    int run = psum[tid] - sum;
#pragma unroll
    for (int j = 0; j < 4; ++j) {
        int idx = lo + j;
        if (idx < NBUCK) ex[idx] = run;
        run += c4[j];
    }
    __syncthreads();
    for (int i = tid; i < NBUCK; i += 256)
        if (h[i] > 0) gb[i] = atomicAdd(&gcursor[i], h[i]);
    for (int i = tid; i < NBUCK; i += 256) h[i] = 0;
    __syncthreads();
#pragma unroll
    for (int j = 0; j < 16; ++j) {
        if (bk[j] >= 0) {
            int r = ex[bk[j]] + atomicAdd(&h[bk[j]], 1);
            stage[r] = pk[j];
            sbkt[r] = (unsigned short)bk[j];
        }
    }
    __syncthreads();
    int tot = min(4096, nE - base);
    for (int i = tid; i < tot; i += 256) {
        int b = sbkt[i];
        elist[gb[b] + (i - ex[b])] = stage[i];
    }
}

// ---------- per-bucket counting sort -> exact per-node CSR + offs ----------
__global__ __launch_bounds__(256) void bucket_csr_kernel(
        const unsigned* __restrict__ elist, const int* __restrict__ gstart,
        int* __restrict__ ssrc, int* __restrict__ offs) {
    __shared__ int cnt[128];
    __shared__ int sc[128];
    int tid = threadIdx.x;
    int b = blockIdx.x;
    if (tid < 128) cnt[tid] = 0;
    __syncthreads();
    int s = gstart[b], e = gstart[b + 1];
    for (int i = s + tid; i < e; i += 256)
        atomicAdd(&cnt[(elist[i] >> 17) & 127], 1);
    __syncthreads();
    int v = 0;
    if (tid < 128) { v = cnt[tid]; sc[tid] = v; }
    __syncthreads();
    for (int off = 1; off < 128; off <<= 1) {
        int t = 0;
        if (tid < 128 && tid >= off) t = sc[tid - off];
        __syncthreads();
        if (tid < 128) sc[tid] += t;
        __syncthreads();
    }
    if (tid < 128) {
        int start = s + sc[tid] - v;
        cnt[tid] = start;
        int node = b * 128 + tid;
        if (node < NN) offs[node] = start;
    }
    if (b == NBUCK - 1 && tid == 0) offs[NN] = NE;
    __syncthreads();
    for (int i = s + tid; i < e; i += 256) {
        unsigned p = elist[i];
        int r = (p >> 17) & 127;
        int pos = atomicAdd(&cnt[r], 1);
        ssrc[pos] = (int)(p & 0x1FFFF);
    }
}

// ---------- compose decode projection into layer-2 weights ----------
__global__ void compose_kernel(const float* __restrict__ w2l, const float* __restrict__ w2r,
                               const float* __restrict__ b2,
                               const float* __restrict__ wd1, const float* __restrict__ bd1,
                               float* __restrict__ wcomp, float* __restrict__ bcomp) {
    int c = threadIdx.x;
    int k = blockIdx.x;
    if (k < C) {
        float wma = 0, wmb = 0, wha = 0, whb = 0;
        for (int j = 0; j < C; ++j) {
            float wt = wd1[j * C + c];
            float wb = wd1[(C + j) * C + c];
            float l = w2l[k * C + j];
            float r = w2r[k * C + j];
            wma += l * wt; wmb += l * wb;
            wha += r * wt; whb += r * wb;
        }
        wcomp[0 * C * C + k * C + c] = wma;
        wcomp[1 * C * C + k * C + c] = wha;
        wcomp[2 * C * C + k * C + c] = wmb;
        wcomp[3 * C * C + k * C + c] = whb;
    } else {
        float ba = bd1[c], bb = 0;
        for (int j = 0; j < C; ++j) {
            float bj = b2[j];
            ba += bj * wd1[j * C + c];
            bb += bj * wd1[(C + j) * C + c];
        }
        bcomp[c] = ba;
        bcomp[C + c] = bb;
    }
}

// ---------- pack W1=[wl;wr] (K=256,N=128) into B-frag layout, f16 ----------
__global__ void pack_w1_kernel(const float* __restrict__ wl, const float* __restrict__ wr,
                               f16* __restrict__ Wh) {
    int t = blockIdx.x * 256 + threadIdx.x;   // [0, 256*128)
    int j = t & 7, l = (t >> 3) & 63;
    int kf = (t >> 9) & 7;
    int nf = t >> 12;
    int k = kf * 32 + ((l >> 4) << 3) + j;
    int n = nf * 16 + (l & 15);
    float w = (k < C) ? wl[k * C + n] : wr[(k - C) * C + n];
    Wh[t] = (f16)w;
}

// ---------- pack composed W2 (K=256,N=256) from wcomp, f16 ----------
__global__ void pack_w2_kernel(const float* __restrict__ wcomp,
                               f16* __restrict__ Wh) {
    int t = blockIdx.x * 256 + threadIdx.x;   // [0, 256*256)
    int j = t & 7, l = (t >> 3) & 63;
    int kf = (t >> 9) & 7;
    int nf = t >> 12;
    int k = kf * 32 + ((l >> 4) << 3) + j;
    int n = nf * 16 + (l & 15);
    int sel = (k >= C ? 1 : 0) + (n >= C ? 2 : 0);
    float w = wcomp[sel * C * C + (k & (C - 1)) * C + (n & (C - 1))];
    Wh[t] = (f16)w;
}

// ---------- gather mean: ONE WAVE per node ----------
// lanes 0-31 take even edges, 32-63 odd edges of the SAME node (no intra-wave
// degree divergence); cross-half reduce via shfl_down(32) at the end.
__global__ __launch_bounds__(256) void gather_mean_f16_kernel(
        const f16* __restrict__ xin, const int* __restrict__ offs,
        const int* __restrict__ ssrc, f16* __restrict__ mean) {
    int gid = blockIdx.x * 256 + threadIdx.x;
    int wid = gid >> 6;
    int lane = threadIdx.x & 63;
    int ch = (lane & 31) * 4;
    int esel = lane >> 5;
    int nw = (gridDim.x * 256) >> 6;
    for (int n = wid; n < NN; n += nw) {
        int start = offs[n];
        int end = offs[n + 1];
        float4 acc = make_float4(0.f, 0.f, 0.f, 0.f);
        for (int e0 = start; e0 < end; e0 += 8) {
#pragma unroll
            for (int u = 0; u < 4; ++u) {
                int e = e0 + 2 * u + esel;
                if (e < end) {
                    f16x4 v = *(const f16x4*)(xin + (size_t)ssrc[e] * C + ch);
                    acc.x += (float)v[0]; acc.y += (float)v[1];
                    acc.z += (float)v[2]; acc.w += (float)v[3];
                }
            }
        }
        acc.x += __shfl_down(acc.x, 32, 64);
        acc.y += __shfl_down(acc.y, 32, 64);
        acc.z += __shfl_down(acc.z, 32, 64);
        acc.w += __shfl_down(acc.w, 32, 64);
        if (lane < 32) {
            float inv = 1.0f / fmaxf((float)(end - start), 1.0f);
            f16x4 m = {(f16)(acc.x * inv), (f16)(acc.y * inv),
                       (f16)(acc.z * inv), (f16)(acc.w * inv)};
            *(f16x4*)(mean + (size_t)n * C + ch) = m;
        }
    }
}

// ---------- f16 MFMA transform: Y = [A0|A1] @ W + bias (f16 weights) ----------
// Compiler-scheduled, (256,4), bijective XCD swizzle so all y-chunks of a
// row-block run on one XCD (A rows L2-reused).
template<int NFT, int RELU, int NCH>
__global__ __launch_bounds__(256, 4) void mfma_transform_f16_kernel(
        const f16* __restrict__ A0, const f16* __restrict__ A1,
        const f16* __restrict__ Bh,
        const float* __restrict__ bias,
        f16* O0, f16* O1) {
    constexpr int KF = 8;
    constexpr int MS = 4;
    constexpr int NF = 4;
    const int nblk = ((NN + 255) / 256) * NCH;   // 391*NCH
    int lin = blockIdx.x;
    int q = nblk >> 3, r = nblk & 7;
    int xcd = lin & 7, idx = lin >> 3;
    int swz = (xcd < r ? xcd * (q + 1) : r * (q + 1) + (xcd - r) * q) + idx;
    int rowblk = swz / NCH;
    int ych = swz - rowblk * NCH;

    int tid = threadIdx.x;
    int w = tid >> 6, l = tid & 63;
    int m0 = rowblk * 256 + w * (MS * 16);
    int nf0 = ych * NF;
    int lr = l & 15;
    int lk = (l >> 4) * 8;

    f32x4 acc[MS][NF];
#pragma unroll
    for (int ms = 0; ms < MS; ++ms)
#pragma unroll
        for (int nf = 0; nf < NF; ++nf)
            acc[ms][nf] = (f32x4){0.0f, 0.0f, 0.0f, 0.0f};

    const f16x8* Bhp = (const f16x8*)Bh;

#pragma unroll
    for (int kf = 0; kf < KF; ++kf) {
        const f16* Asrc = (kf < 4) ? A0 : A1;
        int kofs = (kf & 3) * 32 + lk;
        f16x8 a[MS];
#pragma unroll
        for (int ms = 0; ms < MS; ++ms) {
            int rrow = m0 + ms * 16 + lr;
            rrow = (rrow < NN) ? rrow : (NN - 1);
            a[ms] = *(const f16x8*)(Asrc + (size_t)rrow * C + kofs);
        }
#pragma unroll
        for (int nf = 0; nf < NF; ++nf) {
            f16x8 bh = Bhp[((nf0 + nf) * KF + kf) * 64 + l];
#pragma unroll
            for (int ms = 0; ms < MS; ++ms) {
                acc[ms][nf] = __builtin_amdgcn_mfma_f32_16x16x32_f16(a[ms], bh, acc[ms][nf], 0, 0, 0);
            }
        }
    }

    // epilogue: C/D layout col = lane&15, row = (lane>>4)*4 + i
#pragma unroll
    for (int nf = 0; nf < NF; ++nf) {
        int nfg = nf0 + nf;
        float bv = bias[nfg * 16 + lr];
        f16* O = (NFT == 8) ? O0 : ((nfg < 8) ? O0 : O1);
        int c = ((NFT == 8) ? nfg : (nfg & 7)) * 16 + lr;
#pragma unroll
        for (int ms = 0; ms < MS; ++ms) {
#pragma unroll
            for (int i = 0; i < 4; ++i) {
                int rrow = m0 + ms * 16 + (l >> 4) * 4 + i;
                if (rrow < NN) {
                    float v = acc[ms][nf][i] + bv;
                    if (RELU) v = fmaxf(v, 0.0f);
                    O[(size_t)rrow * C + c] = (f16)v;
                }
            }
        }
    }
}

// ---------- decode (f16 a/b): half-wave per pair, 2 pairs in flight ----------
__global__ __launch_bounds__(256) void decode_kernel(
        const f16* __restrict__ a, const f16* __restrict__ b,
        const int* __restrict__ pu, const int* __restrict__ pv,
        const float* __restrict__ wd2, const float* __restrict__ bd2,
        float* __restrict__ out) {
    int gid = blockIdx.x * 256 + threadIdx.x;
    int hw = gid >> 5;
    int lane = threadIdx.x & 31;
    int nhw = (gridDim.x * 256) >> 5;
    float4 w2 = *(const float4*)&wd2[lane * 4];
    float bout = bd2[0];
    for (int p = hw; p < NP; p += 2 * nhw) {
        int p2 = p + nhw;
        bool ok2 = p2 < NP;
        int u1 = pu[p], v1 = pv[p];
        int u2 = ok2 ? pu[p2] : 0, v2 = ok2 ? pv[p2] : 0;
        f16x4 a1 = *(const f16x4*)(a + (size_t)u1 * C + lane * 4);
        f16x4 b1 = *(const f16x4*)(b + (size_t)v1 * C + lane * 4);
        f16x4 a2 = *(const f16x4*)(a + (size_t)u2 * C + lane * 4);
        f16x4 b2 = *(const f16x4*)(b + (size_t)v2 * C + lane * 4);
        float s1 = fmaxf((float)a1[0] + (float)b1[0], 0.0f) * w2.x
                 + fmaxf((float)a1[1] + (float)b1[1], 0.0f) * w2.y
                 + fmaxf((float)a1[2] + (float)b1[2], 0.0f) * w2.z
                 + fmaxf((float)a1[3] + (float)b1[3], 0.0f) * w2.w;
        float s2 = fmaxf((float)a2[0] + (float)b2[0], 0.0f) * w2.x
                 + fmaxf((float)a2[1] + (float)b2[1], 0.0f) * w2.y
                 + fmaxf((float)a2[2] + (float)b2[2], 0.0f) * w2.z
                 + fmaxf((float)a2[3] + (float)b2[3], 0.0f) * w2.w;
#pragma unroll
        for (int off = 16; off; off >>= 1) {
            s1 += __shfl_down(s1, off, 32);
            s2 += __shfl_down(s2, off, 32);
        }
        if (lane == 0) {
            out[p] = s1 + bout;
            if (ok2) out[p2] = s2 + bout;
        }
    }
}

extern "C" void kernel_launch(void* const* d_in, const int* in_sizes, int n_in,
                              void* d_out, int out_size, void* d_ws, size_t ws_size,
                              hipStream_t stream) {
    const float* x    = (const float*)d_in[0];
    const float* w1_l = (const float*)d_in[1];
    const float* b1   = (const float*)d_in[2];
    const float* w1_r = (const float*)d_in[3];
    const float* w2_l = (const float*)d_in[4];
    const float* b2   = (const float*)d_in[5];
    const float* w2_r = (const float*)d_in[6];
    const float* wd1  = (const float*)d_in[7];
    const float* bd1  = (const float*)d_in[8];
    const float* wd2  = (const float*)d_in[9];
    const float* bd2  = (const float*)d_in[10];
    const int* edge_index = (const int*)d_in[11];
    const int* edge_pairs = (const int*)d_in[12];

    const int* esrc = edge_index;
    const int* edst = edge_index + NE;
    const int* pu = edge_pairs;
    const int* pv = edge_pairs + NP;

    // ws: gcnt|gstart|gcursor|offs | elist | ssrc | xh | mean_h | h1h | a_h | b_h | wcomp | bcomp | packs
    int* gcnt    = (int*)d_ws;
    int* gstart  = gcnt + 1024;
    int* gcursor = gstart + 1024;
    int* offs    = gcursor + 1024;
    unsigned* elist = (unsigned*)(offs + ((NN + 1 + 255) & ~255));
    int* ssrc    = (int*)(elist + NE);
    f16* xh      = (f16*)(ssrc + ((NE + 255) & ~255));
    f16* mean_h  = xh + (size_t)NN * C;
    f16* h1h     = mean_h + (size_t)NN * C;
    f16* a_h     = h1h + (size_t)NN * C;
    f16* b_h     = a_h + (size_t)NN * C;
    float* wcomp = (float*)(b_h + (size_t)NN * C);
    float* bcomp = wcomp + 4 * C * C;
    f16* w1h = (f16*)(bcomp + 2 * C);
    f16* w2h = w1h + 256 * 128;

    hipMemsetAsync(gcnt, 0, sizeof(int) * 1024, stream);

    bin_count_kernel<<<(NE + 8191) / 8192, 256, 0, stream>>>(edst, gcnt, NE);
    bin_scan_kernel<<<1, 1024, 0, stream>>>(gcnt, gstart, gcursor);
    bin_scatter_kernel<<<(NE + 4095) / 4096, 256, 0, stream>>>(esrc, edst, gcursor, elist, NE);
    bucket_csr_kernel<<<NBUCK, 256, 0, stream>>>(elist, gstart, ssrc, offs);

    compose_kernel<<<C + 1, C, 0, stream>>>(w2_l, w2_r, b2, wd1, bd1, wcomp, bcomp);
    pack_w1_kernel<<<128, 256, 0, stream>>>(w1_l, w1_r, w1h);
    pack_w2_kernel<<<256, 256, 0, stream>>>(wcomp, w2h);

    f32_to_f16_kernel<<<(NN * C / 4 + 255) / 256, 256, 0, stream>>>(x, xh, NN * C / 4);

    int rblocks = (NN + 255) / 256;   // 391
    gather_mean_f16_kernel<<<6144, 256, 0, stream>>>(xh, offs, ssrc, mean_h);
    mfma_transform_f16_kernel<8, 1, 2><<<rblocks * 2, 256, 0, stream>>>(
        mean_h, xh, w1h, b1, h1h, nullptr);
    gather_mean_f16_kernel<<<6144, 256, 0, stream>>>(h1h, offs, ssrc, mean_h);
    mfma_transform_f16_kernel<16, 0, 4><<<rblocks * 4, 256, 0, stream>>>(
        mean_h, h1h, w2h, bcomp, a_h, b_h);

    decode_kernel<<<4096, 256, 0, stream>>>(a_h, b_h, pu, pv, wd2, bd2, (float*)d_out);
}

// Round 16
// 332.631 us; speedup vs baseline: 1.2091x; 1.2091x over previous
//
#include <hip/hip_runtime.h>
#include <hip/hip_bf16.h>

#define NN 100000
#define NE 1600000
#define NP 500000
#define C 128
#define NBUCK 782              // buckets of 128 dst nodes: 782*128 = 100096 >= NN

typedef __attribute__((ext_vector_type(4))) float f32x4;
typedef _Float16 f16;
typedef __attribute__((ext_vector_type(4))) _Float16 f16x4;
typedef __attribute__((ext_vector_type(8))) _Float16 f16x8;

// ---------- f32 -> f16 conversion ----------
__global__ __launch_bounds__(256) void f32_to_f16_kernel(
        const float* __restrict__ in, f16* __restrict__ out, int n4) {
    int i = blockIdx.x * 256 + threadIdx.x;
    if (i < n4) {
        float4 v = *(const float4*)&in[i * 4];
        f16x4 h = {(f16)v.x, (f16)v.y, (f16)v.z, (f16)v.w};
        *(f16x4*)&out[i * 4] = h;
    }
}

// ---------- bucket histogram (LDS-staged) ----------
__global__ __launch_bounds__(256) void bin_count_kernel(
        const int* __restrict__ dst, int* __restrict__ gcnt, int nE) {
    __shared__ int h[NBUCK];
    int tid = threadIdx.x;
    for (int i = tid; i < NBUCK; i += 256) h[i] = 0;
    __syncthreads();
    int base = blockIdx.x * 8192;
#pragma unroll
    for (int j = 0; j < 32; ++j) {
        int e = base + tid + j * 256;
        if (e < nE) atomicAdd(&h[dst[e] >> 7], 1);
    }
    __syncthreads();
    for (int i = tid; i < NBUCK; i += 256)
        if (h[i]) atomicAdd(&gcnt[i], h[i]);
}

// ---------- scan bucket counts (one block) ----------
__global__ __launch_bounds__(1024) void bin_scan_kernel(
        const int* __restrict__ gcnt, int* __restrict__ gstart,
        int* __restrict__ gcursor) {
    __shared__ int s[1024];
    int tid = threadIdx.x;
    int v = (tid < NBUCK) ? gcnt[tid] : 0;
    s[tid] = v;
    __syncthreads();
    for (int off = 1; off < 1024; off <<= 1) {
        int t = (tid >= off) ? s[tid - off] : 0;
        __syncthreads();
        s[tid] += t;
        __syncthreads();
    }
    int excl = s[tid] - v;
    if (tid < NBUCK) { gstart[tid] = excl; gcursor[tid] = excl; }
    if (tid == NBUCK - 1) gstart[NBUCK] = excl + v;
}

// ---------- LDS-staged multisplit scatter: coalesced bucket-grouped writes ----------
__global__ __launch_bounds__(256) void bin_scatter_kernel(
        const int* __restrict__ src, const int* __restrict__ dst,
        int* __restrict__ gcursor, unsigned* __restrict__ elist, int nE) {
    __shared__ unsigned stage[4096];
    __shared__ unsigned short sbkt[4096];
    __shared__ int h[NBUCK];
    __shared__ int ex[NBUCK];
    __shared__ int gb[NBUCK];
    __shared__ int psum[256];
    int tid = threadIdx.x;
    for (int i = tid; i < NBUCK; i += 256) h[i] = 0;
    __syncthreads();
    int base = blockIdx.x * 4096;
    unsigned pk[16]; int bk[16];
#pragma unroll
    for (int j = 0; j < 16; ++j) {
        int e = base + tid + j * 256;
        bool ok = e < nE;
        int d = ok ? dst[e] : 0;
        int s = ok ? src[e] : 0;
        bk[j] = ok ? (d >> 7) : -1;
        pk[j] = ((unsigned)(d & 127) << 17) | (unsigned)s;
        if (ok) atomicAdd(&h[bk[j]], 1);
    }
    __syncthreads();
    int lo = tid * 4;
    int c4[4]; int sum = 0;
#pragma unroll
    for (int j = 0; j < 4; ++j) {
        int idx = lo + j;
        c4[j] = (idx < NBUCK) ? h[idx] : 0;
        sum += c4[j];
    }
    psum[tid] = sum;
    __syncthreads();
    for (int off = 1; off < 256; off <<= 1) {
        int t = (tid >= off) ? psum[tid - off] : 0;
        __syncthreads();
        psum[tid] += t;
        __syncthreads();
    }
    int run = psum[tid] - sum;
#pragma unroll
    for (int j = 0; j < 4; ++j) {
        int idx = lo + j;
        if (idx < NBUCK) ex[idx] = run;
        run += c4[j];
    }
    __syncthreads();
    for (int i = tid; i < NBUCK; i += 256)
        if (h[i] > 0) gb[i] = atomicAdd(&gcursor[i], h[i]);
    for (int i = tid; i < NBUCK; i += 256) h[i] = 0;
    __syncthreads();
#pragma unroll
    for (int j = 0; j < 16; ++j) {
        if (bk[j] >= 0) {
            int r = ex[bk[j]] + atomicAdd(&h[bk[j]], 1);
            stage[r] = pk[j];
            sbkt[r] = (unsigned short)bk[j];
        }
    }
    __syncthreads();
    int tot = min(4096, nE - base);
    for (int i = tid; i < tot; i += 256) {
        int b = sbkt[i];
        elist[gb[b] + (i - ex[b])] = stage[i];
    }
}

// ---------- per-bucket counting sort -> exact per-node CSR + offs ----------
__global__ __launch_bounds__(256) void bucket_csr_kernel(
        const unsigned* __restrict__ elist, const int* __restrict__ gstart,
        int* __restrict__ ssrc, int* __restrict__ offs) {
    __shared__ int cnt[128];
    __shared__ int sc[128];
    int tid = threadIdx.x;
    int b = blockIdx.x;
    if (tid < 128) cnt[tid] = 0;
    __syncthreads();
    int s = gstart[b], e = gstart[b + 1];
    for (int i = s + tid; i < e; i += 256)
        atomicAdd(&cnt[(elist[i] >> 17) & 127], 1);
    __syncthreads();
    int v = 0;
    if (tid < 128) { v = cnt[tid]; sc[tid] = v; }
    __syncthreads();
    for (int off = 1; off < 128; off <<= 1) {
        int t = 0;
        if (tid < 128 && tid >= off) t = sc[tid - off];
        __syncthreads();
        if (tid < 128) sc[tid] += t;
        __syncthreads();
    }
    if (tid < 128) {
        int start = s + sc[tid] - v;
        cnt[tid] = start;
        int node = b * 128 + tid;
        if (node < NN) offs[node] = start;
    }
    if (b == NBUCK - 1 && tid == 0) offs[NN] = NE;
    __syncthreads();
    for (int i = s + tid; i < e; i += 256) {
        unsigned p = elist[i];
        int r = (p >> 17) & 127;
        int pos = atomicAdd(&cnt[r], 1);
        ssrc[pos] = (int)(p & 0x1FFFF);
    }
}

// ---------- compose decode projection into layer-2 weights ----------
__global__ void compose_kernel(const float* __restrict__ w2l, const float* __restrict__ w2r,
                               const float* __restrict__ b2,
                               const float* __restrict__ wd1, const float* __restrict__ bd1,
                               float* __restrict__ wcomp, float* __restrict__ bcomp) {
    int c = threadIdx.x;
    int k = blockIdx.x;
    if (k < C) {
        float wma = 0, wmb = 0, wha = 0, whb = 0;
        for (int j = 0; j < C; ++j) {
            float wt = wd1[j * C + c];
            float wb = wd1[(C + j) * C + c];
            float l = w2l[k * C + j];
            float r = w2r[k * C + j];
            wma += l * wt; wmb += l * wb;
            wha += r * wt; whb += r * wb;
        }
        wcomp[0 * C * C + k * C + c] = wma;
        wcomp[1 * C * C + k * C + c] = wha;
        wcomp[2 * C * C + k * C + c] = wmb;
        wcomp[3 * C * C + k * C + c] = whb;
    } else {
        float ba = bd1[c], bb = 0;
        for (int j = 0; j < C; ++j) {
            float bj = b2[j];
            ba += bj * wd1[j * C + c];
            bb += bj * wd1[(C + j) * C + c];
        }
        bcomp[c] = ba;
        bcomp[C + c] = bb;
    }
}

// ---------- pack W1=[wl;wr] (K=256,N=128) into B-frag layout, f16 ----------
__global__ void pack_w1_kernel(const float* __restrict__ wl, const float* __restrict__ wr,
                               f16* __restrict__ Wh) {
    int t = blockIdx.x * 256 + threadIdx.x;   // [0, 256*128)
    int j = t & 7, l = (t >> 3) & 63;
    int kf = (t >> 9) & 7;
    int nf = t >> 12;
    int k = kf * 32 + ((l >> 4) << 3) + j;
    int n = nf * 16 + (l & 15);
    float w = (k < C) ? wl[k * C + n] : wr[(k - C) * C + n];
    Wh[t] = (f16)w;
}

// ---------- pack composed W2 (K=256,N=256) from wcomp, f16 ----------
__global__ void pack_w2_kernel(const float* __restrict__ wcomp,
                               f16* __restrict__ Wh) {
    int t = blockIdx.x * 256 + threadIdx.x;   // [0, 256*256)
    int j = t & 7, l = (t >> 3) & 63;
    int kf = (t >> 9) & 7;
    int nf = t >> 12;
    int k = kf * 32 + ((l >> 4) << 3) + j;
    int n = nf * 16 + (l & 15);
    int sel = (k >= C ? 1 : 0) + (n >= C ? 2 : 0);
    float w = wcomp[sel * C * C + (k & (C - 1)) * C + (n & (C - 1))];
    Wh[t] = (f16)w;
}

// ---------- gather mean (f16 rows): half-wave (32 lanes x f16x4) per node ----------
// 8-deep UNGUARDED load batches in the main loop (MLP >> divergence here;
// round-15's per-load guards collapsed load depth and cost +58%).
__global__ __launch_bounds__(256) void gather_mean_f16_kernel(
        const f16* __restrict__ xin, const int* __restrict__ offs,
        const int* __restrict__ ssrc, f16* __restrict__ mean) {
    int gid = blockIdx.x * 256 + threadIdx.x;
    int hw = gid >> 5;
    int lane = threadIdx.x & 31;
    int nhw = (gridDim.x * 256) >> 5;
    for (int n = hw; n < NN; n += nhw) {
        int start = offs[n];
        int end = offs[n + 1];
        float4 acc = make_float4(0.f, 0.f, 0.f, 0.f);
        int e = start;
        for (; e + 7 < end; e += 8) {
            f16x4 v[8];
#pragma unroll
            for (int u = 0; u < 8; ++u)
                v[u] = *(const f16x4*)(xin + (size_t)ssrc[e + u] * C + lane * 4);
#pragma unroll
            for (int u = 0; u < 8; ++u) {
                acc.x += (float)v[u][0]; acc.y += (float)v[u][1];
                acc.z += (float)v[u][2]; acc.w += (float)v[u][3];
            }
        }
        for (; e < end; ++e) {
            f16x4 v = *(const f16x4*)(xin + (size_t)ssrc[e] * C + lane * 4);
            acc.x += (float)v[0]; acc.y += (float)v[1];
            acc.z += (float)v[2]; acc.w += (float)v[3];
        }
        float inv = 1.0f / fmaxf((float)(end - start), 1.0f);
        f16x4 m = {(f16)(acc.x * inv), (f16)(acc.y * inv),
                   (f16)(acc.z * inv), (f16)(acc.w * inv)};
        *(f16x4*)(mean + (size_t)n * C + lane * 4) = m;
    }
}

// ---------- f16 MFMA transform: Y = [A0|A1] @ W + bias (f16 weights) ----------
// Compiler-scheduled, (256,4), bijective XCD swizzle so all y-chunks of a
// row-block run on one XCD (A rows L2-reused).
template<int NFT, int RELU, int NCH>
__global__ __launch_bounds__(256, 4) void mfma_transform_f16_kernel(
        const f16* __restrict__ A0, const f16* __restrict__ A1,
        const f16* __restrict__ Bh,
        const float* __restrict__ bias,
        f16* O0, f16* O1) {
    constexpr int KF = 8;
    constexpr int MS = 4;
    constexpr int NF = 4;
    const int nblk = ((NN + 255) / 256) * NCH;   // 391*NCH
    int lin = blockIdx.x;
    int q = nblk >> 3, r = nblk & 7;
    int xcd = lin & 7, idx = lin >> 3;
    int swz = (xcd < r ? xcd * (q + 1) : r * (q + 1) + (xcd - r) * q) + idx;
    int rowblk = swz / NCH;
    int ych = swz - rowblk * NCH;

    int tid = threadIdx.x;
    int w = tid >> 6, l = tid & 63;
    int m0 = rowblk * 256 + w * (MS * 16);
    int nf0 = ych * NF;
    int lr = l & 15;
    int lk = (l >> 4) * 8;

    f32x4 acc[MS][NF];
#pragma unroll
    for (int ms = 0; ms < MS; ++ms)
#pragma unroll
        for (int nf = 0; nf < NF; ++nf)
            acc[ms][nf] = (f32x4){0.0f, 0.0f, 0.0f, 0.0f};

    const f16x8* Bhp = (const f16x8*)Bh;

#pragma unroll
    for (int kf = 0; kf < KF; ++kf) {
        const f16* Asrc = (kf < 4) ? A0 : A1;
        int kofs = (kf & 3) * 32 + lk;
        f16x8 a[MS];
#pragma unroll
        for (int ms = 0; ms < MS; ++ms) {
            int rrow = m0 + ms * 16 + lr;
            rrow = (rrow < NN) ? rrow : (NN - 1);
            a[ms] = *(const f16x8*)(Asrc + (size_t)rrow * C + kofs);
        }
#pragma unroll
        for (int nf = 0; nf < NF; ++nf) {
            f16x8 bh = Bhp[((nf0 + nf) * KF + kf) * 64 + l];
#pragma unroll
            for (int ms = 0; ms < MS; ++ms) {
                acc[ms][nf] = __builtin_amdgcn_mfma_f32_16x16x32_f16(a[ms], bh, acc[ms][nf], 0, 0, 0);
            }
        }
    }

    // epilogue: C/D layout col = lane&15, row = (lane>>4)*4 + i
#pragma unroll
    for (int nf = 0; nf < NF; ++nf) {
        int nfg = nf0 + nf;
        float bv = bias[nfg * 16 + lr];
        f16* O = (NFT == 8) ? O0 : ((nfg < 8) ? O0 : O1);
        int c = ((NFT == 8) ? nfg : (nfg & 7)) * 16 + lr;
#pragma unroll
        for (int ms = 0; ms < MS; ++ms) {
#pragma unroll
            for (int i = 0; i < 4; ++i) {
                int rrow = m0 + ms * 16 + (l >> 4) * 4 + i;
                if (rrow < NN) {
                    float v = acc[ms][nf][i] + bv;
                    if (RELU) v = fmaxf(v, 0.0f);
                    O[(size_t)rrow * C + c] = (f16)v;
                }
            }
        }
    }
}

// ---------- decode (f16 a/b): half-wave per pair, 2 pairs in flight ----------
__global__ __launch_bounds__(256) void decode_kernel(
        const f16* __restrict__ a, const f16* __restrict__ b,
        const int* __restrict__ pu, const int* __restrict__ pv,
        const float* __restrict__ wd2, const float* __restrict__ bd2,
        float* __restrict__ out) {
    int gid = blockIdx.x * 256 + threadIdx.x;
    int hw = gid >> 5;
    int lane = threadIdx.x & 31;
    int nhw = (gridDim.x * 256) >> 5;
    float4 w2 = *(const float4*)&wd2[lane * 4];
    float bout = bd2[0];
    for (int p = hw; p < NP; p += 2 * nhw) {
        int p2 = p + nhw;
        bool ok2 = p2 < NP;
        int u1 = pu[p], v1 = pv[p];
        int u2 = ok2 ? pu[p2] : 0, v2 = ok2 ? pv[p2] : 0;
        f16x4 a1 = *(const f16x4*)(a + (size_t)u1 * C + lane * 4);
        f16x4 b1 = *(const f16x4*)(b + (size_t)v1 * C + lane * 4);
        f16x4 a2 = *(const f16x4*)(a + (size_t)u2 * C + lane * 4);
        f16x4 b2 = *(const f16x4*)(b + (size_t)v2 * C + lane * 4);
        float s1 = fmaxf((float)a1[0] + (float)b1[0], 0.0f) * w2.x
                 + fmaxf((float)a1[1] + (float)b1[1], 0.0f) * w2.y
                 + fmaxf((float)a1[2] + (float)b1[2], 0.0f) * w2.z
                 + fmaxf((float)a1[3] + (float)b1[3], 0.0f) * w2.w;
        float s2 = fmaxf((float)a2[0] + (float)b2[0], 0.0f) * w2.x
                 + fmaxf((float)a2[1] + (float)b2[1], 0.0f) * w2.y
                 + fmaxf((float)a2[2] + (float)b2[2], 0.0f) * w2.z
                 + fmaxf((float)a2[3] + (float)b2[3], 0.0f) * w2.w;
#pragma unroll
        for (int off = 16; off; off >>= 1) {
            s1 += __shfl_down(s1, off, 32);
            s2 += __shfl_down(s2, off, 32);
        }
        if (lane == 0) {
            out[p] = s1 + bout;
            if (ok2) out[p2] = s2 + bout;
        }
    }
}

extern "C" void kernel_launch(void* const* d_in, const int* in_sizes, int n_in,
                              void* d_out, int out_size, void* d_ws, size_t ws_size,
                              hipStream_t stream) {
    const float* x    = (const float*)d_in[0];
    const float* w1_l = (const float*)d_in[1];
    const float* b1   = (const float*)d_in[2];
    const float* w1_r = (const float*)d_in[3];
    const float* w2_l = (const float*)d_in[4];
    const float* b2   = (const float*)d_in[5];
    const float* w2_r = (const float*)d_in[6];
    const float* wd1  = (const float*)d_in[7];
    const float* bd1  = (const float*)d_in[8];
    const float* wd2  = (const float*)d_in[9];
    const float* bd2  = (const float*)d_in[10];
    const int* edge_index = (const int*)d_in[11];
    const int* edge_pairs = (const int*)d_in[12];

    const int* esrc = edge_index;
    const int* edst = edge_index + NE;
    const int* pu = edge_pairs;
    const int* pv = edge_pairs + NP;

    // ws: gcnt|gstart|gcursor|offs | elist | ssrc | xh | mean_h | h1h | a_h | b_h | wcomp | bcomp | packs
    int* gcnt    = (int*)d_ws;
    int* gstart  = gcnt + 1024;
    int* gcursor = gstart + 1024;
    int* offs    = gcursor + 1024;
    unsigned* elist = (unsigned*)(offs + ((NN + 1 + 255) & ~255));
    int* ssrc    = (int*)(elist + NE);
    f16* xh      = (f16*)(ssrc + ((NE + 255) & ~255));
    f16* mean_h  = xh + (size_t)NN * C;
    f16* h1h     = mean_h + (size_t)NN * C;
    f16* a_h     = h1h + (size_t)NN * C;
    f16* b_h     = a_h + (size_t)NN * C;
    float* wcomp = (float*)(b_h + (size_t)NN * C);
    float* bcomp = wcomp + 4 * C * C;
    f16* w1h = (f16*)(bcomp + 2 * C);
    f16* w2h = w1h + 256 * 128;

    hipMemsetAsync(gcnt, 0, sizeof(int) * 1024, stream);

    bin_count_kernel<<<(NE + 8191) / 8192, 256, 0, stream>>>(edst, gcnt, NE);
    bin_scan_kernel<<<1, 1024, 0, stream>>>(gcnt, gstart, gcursor);
    bin_scatter_kernel<<<(NE + 4095) / 4096, 256, 0, stream>>>(esrc, edst, gcursor, elist, NE);
    bucket_csr_kernel<<<NBUCK, 256, 0, stream>>>(elist, gstart, ssrc, offs);

    compose_kernel<<<C + 1, C, 0, stream>>>(w2_l, w2_r, b2, wd1, bd1, wcomp, bcomp);
    pack_w1_kernel<<<128, 256, 0, stream>>>(w1_l, w1_r, w1h);
    pack_w2_kernel<<<256, 256, 0, stream>>>(wcomp, w2h);

    f32_to_f16_kernel<<<(NN * C / 4 + 255) / 256, 256, 0, stream>>>(x, xh, NN * C / 4);

    int rblocks = (NN + 255) / 256;   // 391
    gather_mean_f16_kernel<<<6144, 256, 0, stream>>>(xh, offs, ssrc, mean_h);
    mfma_transform_f16_kernel<8, 1, 2><<<rblocks * 2, 256, 0, stream>>>(
        mean_h, xh, w1h, b1, h1h, nullptr);
    gather_mean_f16_kernel<<<6144, 256, 0, stream>>>(h1h, offs, ssrc, mean_h);
    mfma_transform_f16_kernel<16, 0, 4><<<rblocks * 4, 256, 0, stream>>>(
        mean_h, h1h, w2h, bcomp, a_h, b_h);

    decode_kernel<<<4096, 256, 0, stream>>>(a_h, b_h, pu, pv, wd2, bd2, (float*)d_out);
}